// Round 1
// baseline (149.572 us; speedup 1.0000x reference)
//
#include <hip/hip_runtime.h>
#include <hip/hip_bf16.h>

// FastAttention (Performer linear attention), B=4 H=8 N=4096 D=F=64, fp32.
// Two-pass fused implementation:
//   pass1: k' = exp(k @ proj^T); ksum[f] = sum_n k'; ctx[f] = sum_n k'[f]*v[f]
//          -> ws per head: [0..63]=ksum, [64..127]=ctx  (fp32 atomics)
//   pass2: q' = exp(q @ proj^T); denom = q' . (ksum+1e-6); out = q'*ctx/denom
// Feature-map matmul runs on bf16 MFMA (16x16x32); accumulation fp32.

#define NHEADS 32          // B*H
#define SEQ    4096
#define DDIM   64

typedef __attribute__((ext_vector_type(8))) short short8;
typedef __attribute__((ext_vector_type(4))) float floatx4;

__device__ __forceinline__ short f2bf(float x) {
    // fp32 -> bf16 round-to-nearest-even (bit trick)
    unsigned int u = __float_as_uint(x);
    u += 0x7fffu + ((u >> 16) & 1u);
    return (short)(u >> 16);
}

__device__ __forceinline__ short8 load8_bf16(const float* __restrict__ p) {
    floatx4 a = *(const floatx4*)p;
    floatx4 b = *(const floatx4*)(p + 4);
    short8 t;
    t[0] = f2bf(a[0]); t[1] = f2bf(a[1]); t[2] = f2bf(a[2]); t[3] = f2bf(a[3]);
    t[4] = f2bf(b[0]); t[5] = f2bf(b[1]); t[6] = f2bf(b[2]); t[7] = f2bf(b[3]);
    return t;
}

// B fragments (proj) for D=A*B with A=rows x d, B=d x f.
// B[k][n] = proj[f=n][d=k]; lane holds B[k=(lane>>4)*8+j + 32*half][n=ft*16+(lane&15)]
__device__ __forceinline__ void load_bfrag(const float* __restrict__ proj,
                                           int fp, int g, short8 bfrag[4][2]) {
#pragma unroll
    for (int ft = 0; ft < 4; ++ft)
#pragma unroll
        for (int half = 0; half < 2; ++half)
            bfrag[ft][half] = load8_bf16(proj + (ft * 16 + fp) * DDIM + half * 32 + g * 8);
}

__global__ __launch_bounds__(256) void fa_pass1(const float* __restrict__ K,
                                                const float* __restrict__ V,
                                                const float* __restrict__ proj,
                                                float* __restrict__ ws) {
    const int head = blockIdx.x >> 4;   // 32 heads x 16 segments of 256 rows
    const int seg  = blockIdx.x & 15;
    const int tid  = threadIdx.x;
    const int w    = tid >> 6;          // wave 0..3
    const int lane = tid & 63;
    const int fp   = lane & 15;         // A-row within tile / C-col (f')
    const int g    = lane >> 4;         // quad

    short8 bfrag[4][2];
    load_bfrag(proj, fp, g, bfrag);

    float ksum[4] = {0.f, 0.f, 0.f, 0.f};
    float ctx[4]  = {0.f, 0.f, 0.f, 0.f};

    const long hbase = (long)head * SEQ;

#pragma unroll
    for (int it = 0; it < 4; ++it) {
        const int row0 = seg * 256 + it * 64 + w * 16;  // tile base within head
        const float* ap = K + (hbase + row0 + fp) * DDIM;
        short8 afrag0 = load8_bf16(ap + g * 8);        // d = 0..31
        short8 afrag1 = load8_bf16(ap + 32 + g * 8);   // d = 32..63

        floatx4 acc[4];
#pragma unroll
        for (int ft = 0; ft < 4; ++ft) {
            floatx4 z = {0.f, 0.f, 0.f, 0.f};
            z = __builtin_amdgcn_mfma_f32_16x16x32_bf16(afrag0, bfrag[ft][0], z, 0, 0, 0);
            z = __builtin_amdgcn_mfma_f32_16x16x32_bf16(afrag1, bfrag[ft][1], z, 0, 0, 0);
            acc[ft] = z;
        }

        // C layout: col f = ft*16+fp, row = row0 + g*4 + r
#pragma unroll
        for (int ft = 0; ft < 4; ++ft) {
#pragma unroll
            for (int r = 0; r < 4; ++r) {
                float kp = __expf(acc[ft][r]);
                float vv = V[(hbase + row0 + g * 4 + r) * DDIM + ft * 16 + fp];
                ksum[ft] += kp;
                ctx[ft]  += kp * vv;
            }
        }
    }

    // reduce across g (rows) within wave: lanes xor 16, 32
#pragma unroll
    for (int ft = 0; ft < 4; ++ft) {
        ksum[ft] += __shfl_xor(ksum[ft], 16); ksum[ft] += __shfl_xor(ksum[ft], 32);
        ctx[ft]  += __shfl_xor(ctx[ft], 16);  ctx[ft]  += __shfl_xor(ctx[ft], 32);
    }

    __shared__ float red[4][128];
    if (lane < 16) {
#pragma unroll
        for (int ft = 0; ft < 4; ++ft) {
            red[w][ft * 16 + fp]      = ksum[ft];
            red[w][64 + ft * 16 + fp] = ctx[ft];
        }
    }
    __syncthreads();
    if (tid < 128) {
        float s = red[0][tid] + red[1][tid] + red[2][tid] + red[3][tid];
        atomicAdd(ws + head * 128 + tid, s);
    }
}

__global__ __launch_bounds__(256) void fa_pass2(const float* __restrict__ Q,
                                                const float* __restrict__ proj,
                                                const float* __restrict__ ws,
                                                float* __restrict__ out) {
    const int head = blockIdx.x >> 6;   // 32 heads x 64 segments of 64 rows
    const int seg  = blockIdx.x & 63;
    const int tid  = threadIdx.x;
    const int w    = tid >> 6;
    const int lane = tid & 63;
    const int fp   = lane & 15;
    const int g    = lane >> 4;

    short8 bfrag[4][2];
    load_bfrag(proj, fp, g, bfrag);

    float ksr[4], ctxr[4];
#pragma unroll
    for (int ft = 0; ft < 4; ++ft) {
        ksr[ft]  = ws[head * 128 + ft * 16 + fp] + 1e-6f;
        ctxr[ft] = ws[head * 128 + 64 + ft * 16 + fp];
    }

    const long hbase = (long)head * SEQ;
    const int row0 = seg * 64 + w * 16;
    const float* ap = Q + (hbase + row0 + fp) * DDIM;
    short8 afrag0 = load8_bf16(ap + g * 8);
    short8 afrag1 = load8_bf16(ap + 32 + g * 8);

    float qp[4][4];
    float denom[4] = {0.f, 0.f, 0.f, 0.f};
#pragma unroll
    for (int ft = 0; ft < 4; ++ft) {
        floatx4 z = {0.f, 0.f, 0.f, 0.f};
        z = __builtin_amdgcn_mfma_f32_16x16x32_bf16(afrag0, bfrag[ft][0], z, 0, 0, 0);
        z = __builtin_amdgcn_mfma_f32_16x16x32_bf16(afrag1, bfrag[ft][1], z, 0, 0, 0);
#pragma unroll
        for (int r = 0; r < 4; ++r) {
            float e = __expf(z[r]);
            qp[ft][r] = e;
            denom[r] += e * ksr[ft];
        }
    }

    // reduce denom over f' lanes (xor 1,2,4,8 stays within the 16-lane quad group)
#pragma unroll
    for (int r = 0; r < 4; ++r) {
        denom[r] += __shfl_xor(denom[r], 1);
        denom[r] += __shfl_xor(denom[r], 2);
        denom[r] += __shfl_xor(denom[r], 4);
        denom[r] += __shfl_xor(denom[r], 8);
        denom[r] = 1.0f / denom[r];
    }

#pragma unroll
    for (int ft = 0; ft < 4; ++ft)
#pragma unroll
        for (int r = 0; r < 4; ++r)
            out[(hbase + row0 + g * 4 + r) * DDIM + ft * 16 + fp] =
                qp[ft][r] * ctxr[ft] * denom[r];
}

extern "C" void kernel_launch(void* const* d_in, const int* in_sizes, int n_in,
                              void* d_out, int out_size, void* d_ws, size_t ws_size,
                              hipStream_t stream) {
    const float* q    = (const float*)d_in[0];
    const float* k    = (const float*)d_in[1];
    const float* v    = (const float*)d_in[2];
    const float* proj = (const float*)d_in[3];
    float* out = (float*)d_out;
    float* ws  = (float*)d_ws;   // 32 heads * 128 floats = 16 KB

    hipMemsetAsync(ws, 0, NHEADS * 128 * sizeof(float), stream);
    fa_pass1<<<NHEADS * 16, 256, 0, stream>>>(k, v, proj, ws);
    fa_pass2<<<NHEADS * 64, 256, 0, stream>>>(q, proj, ws, out);
}

// Round 2
// 139.649 us; speedup vs baseline: 1.0711x; 1.0711x over previous
//
#include <hip/hip_runtime.h>
#include <hip/hip_bf16.h>

// FastAttention (Performer linear attention), B=4 H=8 N=4096 D=F=64, fp32.
//   prep : zero per-head accumulators; convert proj -> bf16 fragment table
//   pass1: k' = exp(k @ proj^T); ksum[f] = sum_n k'; ctx[f] = sum_n k'[f]*v[f]
//   pass2: q' = exp(q @ proj^T); denom = q' . (ksum+1e-6); out = q'*ctx/denom
// Feature-map matmul on bf16 MFMA 16x16x32; all accumulation fp32.
//
// ws layout (floats): [0 .. 4096)  = 32 heads x (64 ksum + 64 ctx) accumulators
//                     [4096 .. )   = proj bf16 fragment table, 4096 shorts (8 KB)
//                     frag table index: (ft*2+half)*512 + lane*8 + j

#define NHEADS 32
#define SEQ    4096
#define DDIM   64
#define ACC_FLOATS (NHEADS * 128)

typedef __attribute__((ext_vector_type(8))) short short8;
typedef __attribute__((ext_vector_type(4))) float floatx4;

__device__ __forceinline__ short f2bf(float x) {
    unsigned int u = __float_as_uint(x);
    u += 0x7fffu + ((u >> 16) & 1u);
    return (short)(u >> 16);
}

__device__ __forceinline__ short8 load8_bf16(const float* __restrict__ p) {
    floatx4 a = *(const floatx4*)p;
    floatx4 b = *(const floatx4*)(p + 4);
    short8 t;
    t[0] = f2bf(a[0]); t[1] = f2bf(a[1]); t[2] = f2bf(a[2]); t[3] = f2bf(a[3]);
    t[4] = f2bf(b[0]); t[5] = f2bf(b[1]); t[6] = f2bf(b[2]); t[7] = f2bf(b[3]);
    return t;
}

// Load prepped B fragments: one coalesced 16B load per (ft,half).
__device__ __forceinline__ void load_bfrag_ws(const short* __restrict__ pbf,
                                              int lane, short8 bfrag[4][2]) {
#pragma unroll
    for (int ft = 0; ft < 4; ++ft)
#pragma unroll
        for (int half = 0; half < 2; ++half)
            bfrag[ft][half] = *(const short8*)(pbf + (ft * 2 + half) * 512 + lane * 8);
}

// blocks 0..31: zero accumulators. block 32: build proj bf16 fragment table.
__global__ __launch_bounds__(128) void fa_prep(const float* __restrict__ proj,
                                               float* __restrict__ ws) {
    const int tid = threadIdx.x;
    if (blockIdx.x < 32) {
        ws[blockIdx.x * 128 + tid] = 0.0f;
        return;
    }
    short* pbf = (short*)(ws + ACC_FLOATS);
#pragma unroll
    for (int i = 0; i < 32; ++i) {
        int idx  = tid * 32 + i;          // 0..4095
        int ft2h = idx >> 9;              // (ft*2+half)
        int rem  = idx & 511;
        int lane = rem >> 3;
        int j    = rem & 7;
        int ft   = ft2h >> 1;
        int half = ft2h & 1;
        int fp   = lane & 15;
        int g    = lane >> 4;
        pbf[idx] = f2bf(proj[(ft * 16 + fp) * DDIM + half * 32 + g * 8 + j]);
    }
}

__global__ __launch_bounds__(256) void fa_pass1(const float* __restrict__ K,
                                                const float* __restrict__ V,
                                                float* __restrict__ ws) {
    const int head = blockIdx.x >> 5;   // 32 heads x 32 segments of 128 rows
    const int seg  = blockIdx.x & 31;
    const int tid  = threadIdx.x;
    const int w    = tid >> 6;
    const int lane = tid & 63;
    const int fp   = lane & 15;
    const int g    = lane >> 4;

    const short* pbf = (const short*)(ws + ACC_FLOATS);
    short8 bfrag[4][2];
    load_bfrag_ws(pbf, lane, bfrag);

    float ksum[4] = {0.f, 0.f, 0.f, 0.f};
    float ctx[4]  = {0.f, 0.f, 0.f, 0.f};

    const long hbase = (long)head * SEQ;

#pragma unroll
    for (int it = 0; it < 2; ++it) {
        const int row0 = seg * 128 + it * 64 + w * 16;
        const float* ap = K + (hbase + row0 + fp) * DDIM;
        short8 afrag0 = load8_bf16(ap + g * 8);
        short8 afrag1 = load8_bf16(ap + 32 + g * 8);

        floatx4 acc[4];
#pragma unroll
        for (int ft = 0; ft < 4; ++ft) {
            floatx4 z = {0.f, 0.f, 0.f, 0.f};
            z = __builtin_amdgcn_mfma_f32_16x16x32_bf16(afrag0, bfrag[ft][0], z, 0, 0, 0);
            z = __builtin_amdgcn_mfma_f32_16x16x32_bf16(afrag1, bfrag[ft][1], z, 0, 0, 0);
            acc[ft] = z;
        }

        // C layout: col f = ft*16+fp, row = row0 + g*4 + r
#pragma unroll
        for (int ft = 0; ft < 4; ++ft) {
#pragma unroll
            for (int r = 0; r < 4; ++r) {
                float kp = __expf(acc[ft][r]);
                float vv = V[(hbase + row0 + g * 4 + r) * DDIM + ft * 16 + fp];
                ksum[ft] += kp;
                ctx[ft]  += kp * vv;
            }
        }
    }

#pragma unroll
    for (int ft = 0; ft < 4; ++ft) {
        ksum[ft] += __shfl_xor(ksum[ft], 16); ksum[ft] += __shfl_xor(ksum[ft], 32);
        ctx[ft]  += __shfl_xor(ctx[ft], 16);  ctx[ft]  += __shfl_xor(ctx[ft], 32);
    }

    __shared__ float red[4][128];
    if (lane < 16) {
#pragma unroll
        for (int ft = 0; ft < 4; ++ft) {
            red[w][ft * 16 + fp]      = ksum[ft];
            red[w][64 + ft * 16 + fp] = ctx[ft];
        }
    }
    __syncthreads();
    if (tid < 128) {
        float s = red[0][tid] + red[1][tid] + red[2][tid] + red[3][tid];
        atomicAdd(ws + head * 128 + tid, s);
    }
}

__global__ __launch_bounds__(256) void fa_pass2(const float* __restrict__ Q,
                                                const float* __restrict__ ws,
                                                float* __restrict__ out) {
    const int head = blockIdx.x >> 6;   // 32 heads x 64 segments of 64 rows
    const int seg  = blockIdx.x & 63;
    const int tid  = threadIdx.x;
    const int w    = tid >> 6;
    const int lane = tid & 63;
    const int fp   = lane & 15;
    const int g    = lane >> 4;

    const short* pbf = (const short*)(ws + ACC_FLOATS);
    short8 bfrag[4][2];
    load_bfrag_ws(pbf, lane, bfrag);

    float ksr[4], ctxr[4];
#pragma unroll
    for (int ft = 0; ft < 4; ++ft) {
        ksr[ft]  = ws[head * 128 + ft * 16 + fp] + 1e-6f;
        ctxr[ft] = ws[head * 128 + 64 + ft * 16 + fp];
    }

    const long hbase = (long)head * SEQ;
    const int row0 = seg * 64 + w * 16;
    const float* ap = Q + (hbase + row0 + fp) * DDIM;
    short8 afrag0 = load8_bf16(ap + g * 8);
    short8 afrag1 = load8_bf16(ap + 32 + g * 8);

    float qp[4][4];
    float denom[4] = {0.f, 0.f, 0.f, 0.f};
#pragma unroll
    for (int ft = 0; ft < 4; ++ft) {
        floatx4 z = {0.f, 0.f, 0.f, 0.f};
        z = __builtin_amdgcn_mfma_f32_16x16x32_bf16(afrag0, bfrag[ft][0], z, 0, 0, 0);
        z = __builtin_amdgcn_mfma_f32_16x16x32_bf16(afrag1, bfrag[ft][1], z, 0, 0, 0);
#pragma unroll
        for (int r = 0; r < 4; ++r) {
            float e = __expf(z[r]);
            qp[ft][r] = e;
            denom[r] += e * ksr[ft];
        }
    }

#pragma unroll
    for (int r = 0; r < 4; ++r) {
        denom[r] += __shfl_xor(denom[r], 1);
        denom[r] += __shfl_xor(denom[r], 2);
        denom[r] += __shfl_xor(denom[r], 4);
        denom[r] += __shfl_xor(denom[r], 8);
        denom[r] = 1.0f / denom[r];
    }

#pragma unroll
    for (int ft = 0; ft < 4; ++ft)
#pragma unroll
        for (int r = 0; r < 4; ++r)
            out[(hbase + row0 + g * 4 + r) * DDIM + ft * 16 + fp] =
                qp[ft][r] * ctxr[ft] * denom[r];
}

extern "C" void kernel_launch(void* const* d_in, const int* in_sizes, int n_in,
                              void* d_out, int out_size, void* d_ws, size_t ws_size,
                              hipStream_t stream) {
    const float* q    = (const float*)d_in[0];
    const float* k    = (const float*)d_in[1];
    const float* v    = (const float*)d_in[2];
    const float* proj = (const float*)d_in[3];
    float* out = (float*)d_out;
    float* ws  = (float*)d_ws;

    fa_prep<<<33, 128, 0, stream>>>(proj, ws);
    fa_pass1<<<NHEADS * 32, 256, 0, stream>>>(k, v, ws);
    fa_pass2<<<NHEADS * 64, 256, 0, stream>>>(q, ws, out);
}

// Round 3
// 137.576 us; speedup vs baseline: 1.0872x; 1.0151x over previous
//
#include <hip/hip_runtime.h>
#include <hip/hip_bf16.h>

// FastAttention (Performer linear attention), B=4 H=8 N=4096 D=F=64, fp32.
//   prep : zero per-head accumulators; build proj*log2(e) bf16 fragment table
//   pass1: k' = exp(k @ proj^T); ksum[f] = sum_n k'; ctx[f] = sum_n k'[f]*v[f]
//   pass2: q' = exp(q @ proj^T); denom = q' . (ksum+1e-6); out = q'*ctx/denom
// Feature-map matmul on bf16 MFMA 16x16x32; all accumulation fp32.
// Column permutation trick: MFMA tile ft computes output feature f = fp*4+ft
// (fp = lane&15), so each lane holds 4 CONSECUTIVE f values -> V loads,
// ksum/ctx loads and out stores are all dwordx4.
//
// ws layout (floats): [0 .. 4096)  = 32 heads x (64 ksum + 64 ctx) accumulators
//                     [4096 .. )   = proj bf16 fragment table, 4096 shorts
//                     table index: (ft*2+half)*512 + lane*8 + j
//                     value: bf16( proj[fp*4+ft][half*32+g*8+j] * log2(e) )

#define NHEADS 32
#define SEQ    4096
#define DDIM   64
#define ACC_FLOATS (NHEADS * 128)
#define LOG2E 1.44269504088896341f

typedef __attribute__((ext_vector_type(8))) short short8;
typedef __attribute__((ext_vector_type(4))) float floatx4;

__device__ __forceinline__ short f2bf(float x) {
    unsigned int u = __float_as_uint(x);
    u += 0x7fffu + ((u >> 16) & 1u);
    return (short)(u >> 16);
}

__device__ __forceinline__ short8 load8_bf16(const float* __restrict__ p) {
    floatx4 a = *(const floatx4*)p;
    floatx4 b = *(const floatx4*)(p + 4);
    short8 t;
    t[0] = f2bf(a[0]); t[1] = f2bf(a[1]); t[2] = f2bf(a[2]); t[3] = f2bf(a[3]);
    t[4] = f2bf(b[0]); t[5] = f2bf(b[1]); t[6] = f2bf(b[2]); t[7] = f2bf(b[3]);
    return t;
}

__device__ __forceinline__ void load_bfrag_ws(const short* __restrict__ pbf,
                                              int lane, short8 bfrag[4][2]) {
#pragma unroll
    for (int ft = 0; ft < 4; ++ft)
#pragma unroll
        for (int half = 0; half < 2; ++half)
            bfrag[ft][half] = *(const short8*)(pbf + (ft * 2 + half) * 512 + lane * 8);
}

// blocks 0..31: zero accumulators. block 32: build proj bf16 fragment table.
__global__ __launch_bounds__(128) void fa_prep(const float* __restrict__ proj,
                                               float* __restrict__ ws) {
    const int tid = threadIdx.x;
    if (blockIdx.x < 32) {
        ws[blockIdx.x * 128 + tid] = 0.0f;
        return;
    }
    short* pbf = (short*)(ws + ACC_FLOATS);
#pragma unroll
    for (int i = 0; i < 32; ++i) {
        int idx  = tid * 32 + i;          // 0..4095
        int ft2h = idx >> 9;              // (ft*2+half)
        int rem  = idx & 511;
        int lane = rem >> 3;
        int j    = rem & 7;
        int ft   = ft2h >> 1;
        int half = ft2h & 1;
        int fp   = lane & 15;
        int g    = lane >> 4;
        pbf[idx] = f2bf(proj[(fp * 4 + ft) * DDIM + half * 32 + g * 8 + j] * LOG2E);
    }
}

__global__ __launch_bounds__(256) void fa_pass1(const float* __restrict__ K,
                                                const float* __restrict__ V,
                                                float* __restrict__ ws) {
    const int head = blockIdx.x >> 5;   // 32 heads x 32 segments of 128 rows
    const int seg  = blockIdx.x & 31;
    const int tid  = threadIdx.x;
    const int w    = tid >> 6;
    const int lane = tid & 63;
    const int fp   = lane & 15;
    const int g    = lane >> 4;

    const short* pbf = (const short*)(ws + ACC_FLOATS);
    short8 bfrag[4][2];
    load_bfrag_ws(pbf, lane, bfrag);

    float ksum[4] = {0.f, 0.f, 0.f, 0.f};
    float ctx[4]  = {0.f, 0.f, 0.f, 0.f};

    const long hbase = (long)head * SEQ;

#pragma unroll
    for (int it = 0; it < 2; ++it) {
        const int row0 = seg * 128 + it * 64 + w * 16;
        const float* ap = K + (hbase + row0 + fp) * DDIM;
        short8 afrag0 = load8_bf16(ap + g * 8);
        short8 afrag1 = load8_bf16(ap + 32 + g * 8);

        floatx4 acc[4];
#pragma unroll
        for (int ft = 0; ft < 4; ++ft) {
            floatx4 z = {0.f, 0.f, 0.f, 0.f};
            z = __builtin_amdgcn_mfma_f32_16x16x32_bf16(afrag0, bfrag[ft][0], z, 0, 0, 0);
            z = __builtin_amdgcn_mfma_f32_16x16x32_bf16(afrag1, bfrag[ft][1], z, 0, 0, 0);
            acc[ft] = z;
        }

        // C layout: col f = fp*4+ft, row = row0 + g*4 + r
#pragma unroll
        for (int r = 0; r < 4; ++r) {
            const floatx4 vv = *(const floatx4*)(V + (hbase + row0 + g * 4 + r) * DDIM + fp * 4);
#pragma unroll
            for (int ft = 0; ft < 4; ++ft) {
                float kp = __builtin_amdgcn_exp2f(acc[ft][r]);
                ksum[ft] += kp;
                ctx[ft]  += kp * vv[ft];
            }
        }
    }

#pragma unroll
    for (int ft = 0; ft < 4; ++ft) {
        ksum[ft] += __shfl_xor(ksum[ft], 16); ksum[ft] += __shfl_xor(ksum[ft], 32);
        ctx[ft]  += __shfl_xor(ctx[ft], 16);  ctx[ft]  += __shfl_xor(ctx[ft], 32);
    }

    __shared__ float red[4][128];
    if (lane < 16) {
#pragma unroll
        for (int ft = 0; ft < 4; ++ft) {
            red[w][fp * 4 + ft]      = ksum[ft];
            red[w][64 + fp * 4 + ft] = ctx[ft];
        }
    }
    __syncthreads();
    if (tid < 128) {
        float s = red[0][tid] + red[1][tid] + red[2][tid] + red[3][tid];
        atomicAdd(ws + head * 128 + tid, s);
    }
}

__global__ __launch_bounds__(256) void fa_pass2(const float* __restrict__ Q,
                                                const float* __restrict__ ws,
                                                float* __restrict__ out) {
    const int head = blockIdx.x >> 6;   // 32 heads x 64 segments of 64 rows
    const int seg  = blockIdx.x & 63;
    const int tid  = threadIdx.x;
    const int w    = tid >> 6;
    const int lane = tid & 63;
    const int fp   = lane & 15;
    const int g    = lane >> 4;

    const short* pbf = (const short*)(ws + ACC_FLOATS);
    short8 bfrag[4][2];
    load_bfrag_ws(pbf, lane, bfrag);

    floatx4 ksr  = *(const floatx4*)(ws + head * 128 + fp * 4);
    floatx4 ctxr = *(const floatx4*)(ws + head * 128 + 64 + fp * 4);
#pragma unroll
    for (int ft = 0; ft < 4; ++ft) ksr[ft] += 1e-6f;

    const long hbase = (long)head * SEQ;
    const int row0 = seg * 64 + w * 16;
    const float* ap = Q + (hbase + row0 + fp) * DDIM;
    short8 afrag0 = load8_bf16(ap + g * 8);
    short8 afrag1 = load8_bf16(ap + 32 + g * 8);

    float qp[4][4];
    float denom[4] = {0.f, 0.f, 0.f, 0.f};
#pragma unroll
    for (int ft = 0; ft < 4; ++ft) {
        floatx4 z = {0.f, 0.f, 0.f, 0.f};
        z = __builtin_amdgcn_mfma_f32_16x16x32_bf16(afrag0, bfrag[ft][0], z, 0, 0, 0);
        z = __builtin_amdgcn_mfma_f32_16x16x32_bf16(afrag1, bfrag[ft][1], z, 0, 0, 0);
#pragma unroll
        for (int r = 0; r < 4; ++r) {
            float e = __builtin_amdgcn_exp2f(z[r]);
            qp[ft][r] = e;
            denom[r] += e * ksr[ft];
        }
    }

#pragma unroll
    for (int r = 0; r < 4; ++r) {
        denom[r] += __shfl_xor(denom[r], 1);
        denom[r] += __shfl_xor(denom[r], 2);
        denom[r] += __shfl_xor(denom[r], 4);
        denom[r] += __shfl_xor(denom[r], 8);
        denom[r] = 1.0f / denom[r];
    }

#pragma unroll
    for (int r = 0; r < 4; ++r) {
        floatx4 o;
#pragma unroll
        for (int ft = 0; ft < 4; ++ft)
            o[ft] = qp[ft][r] * ctxr[ft] * denom[r];
        *(floatx4*)(out + (hbase + row0 + g * 4 + r) * DDIM + fp * 4) = o;
    }
}

extern "C" void kernel_launch(void* const* d_in, const int* in_sizes, int n_in,
                              void* d_out, int out_size, void* d_ws, size_t ws_size,
                              hipStream_t stream) {
    const float* q    = (const float*)d_in[0];
    const float* k    = (const float*)d_in[1];
    const float* v    = (const float*)d_in[2];
    const float* proj = (const float*)d_in[3];
    float* out = (float*)d_out;
    float* ws  = (float*)d_ws;

    fa_prep<<<33, 128, 0, stream>>>(proj, ws);
    fa_pass1<<<NHEADS * 32, 256, 0, stream>>>(k, v, ws);
    fa_pass2<<<NHEADS * 64, 256, 0, stream>>>(q, ws, out);
}